// Round 9
// baseline (87.225 us; speedup 1.0000x reference)
//
#include <hip/hip_runtime.h>
#include <hip/hip_bf16.h>
#include <math.h>

#define DIM     2048
#define LEVELS  100
#define TSN     32768
#define NBLK    1024
#define NSPLIT  32
#define PACK_BLOCKS 200   // 8 tables x 25 level-groups (4 levels/block)
#define ZERO_BLOCKS 32    // zero partial2 (32 rows x DIM)

// map value in [-3,3] to level index 0..99 (round-half-even like jnp.round)
__device__ __forceinline__ int lvl100(float v) {
    float f = ((v + 3.0f) / 6.0f) * 99.0f;
    int k = (int)rintf(f);
    return min(max(k, 0), LEVELS - 1);
}

// ---------------------------------------------------------------------------
// Fused prep: blocks [0,200) pack the 8 bipolar tables into permuted sign
// words; blocks [200,232) zero partial2; remaining blocks compute per-sample
// indices.
// packed2[tab][level][l] (uint32): bit (4k+j) = sign(W[tab][level][256k+4l+j])
// so lane l of a wave owns dims {256k+4l+j}.
// ---------------------------------------------------------------------------
__global__ __launch_bounds__(256) void prep_k(
    const float* __restrict__ w0, const float* __restrict__ w1,
    const float* __restrict__ w2, const float* __restrict__ w3,
    const float* __restrict__ w4, const float* __restrict__ w5,
    const float* __restrict__ w6, const float* __restrict__ w7,
    const float* __restrict__ inp,
    unsigned int* __restrict__ packed2,
    unsigned long long* __restrict__ sidx,
    unsigned int* __restrict__ tidx,
    float* __restrict__ partial2, int n)
{
    if (blockIdx.x < PACK_BLOCKS) {
        int tab = blockIdx.x / 25;
        int lg  = blockIdx.x - tab * 25;
        int l   = threadIdx.x & 63;
        int level = lg * 4 + (threadIdx.x >> 6);
        const float* w;
        switch (tab) {
            case 0: w = w0; break; case 1: w = w1; break;
            case 2: w = w2; break; case 3: w = w3; break;
            case 4: w = w4; break; case 5: w = w5; break;
            case 6: w = w6; break; default: w = w7; break;
        }
        const float* base = w + (size_t)level * DIM + 4 * l;
        unsigned int word = 0;
        #pragma unroll
        for (int k = 0; k < 8; ++k) {
            float4 a = *(const float4*)(base + 256 * k);
            word |= (a.x < 0.f ? 1u : 0u) << (4 * k);
            word |= (a.y < 0.f ? 1u : 0u) << (4 * k + 1);
            word |= (a.z < 0.f ? 1u : 0u) << (4 * k + 2);
            word |= (a.w < 0.f ? 1u : 0u) << (4 * k + 3);
        }
        packed2[(tab * LEVELS + level) * 64 + l] = word;
        return;
    }
    if (blockIdx.x < PACK_BLOCKS + ZERO_BLOCKS) {
        int row = blockIdx.x - PACK_BLOCKS;
        float4 z = make_float4(0.f, 0.f, 0.f, 0.f);
        float4* p = (float4*)(partial2 + (size_t)row * DIM);
        p[threadIdx.x] = z;
        p[threadIdx.x + 256] = z;
        return;
    }
    int i = (blockIdx.x - PACK_BLOCKS - ZERO_BLOCKS) * 256 + threadIdx.x;
    if (i >= n) return;
    float t0 = inp[0];
    float ti = inp[i * 4] - t0;
    float x = inp[i * 4 + 1], y = inp[i * 4 + 2], z = inp[i * 4 + 3];
    float xc = fminf(fmaxf(x, -3.f), 3.f);
    float yc = fminf(fmaxf(y, -3.f), 3.f);
    float zc = fminf(fmaxf(z, -3.f), 3.f);
    unsigned long long ix = (unsigned long long)lvl100(xc);
    unsigned long long iy = (unsigned long long)lvl100(yc);
    unsigned long long iz = (unsigned long long)lvl100(zc);
    float mag = sqrtf((x * x + y * y) + z * z);   // unclipped, ref assoc order
    unsigned long long im = (unsigned long long)lvl100(mag);
    float jx = 0.f, jy = 0.f, jz = 0.f;
    if (i > 0) {
        float tp = inp[(i - 1) * 4] - t0;
        float dt = ti - tp;                        // dt from offset times, as ref
        jx = (x - inp[(i - 1) * 4 + 1]) / dt;
        jy = (y - inp[(i - 1) * 4 + 2]) / dt;
        jz = (z - inp[(i - 1) * 4 + 3]) / dt;
    }
    unsigned long long ixj = (unsigned long long)lvl100(fminf(fmaxf(jx, -3.f), 3.f));
    unsigned long long iyj = (unsigned long long)lvl100(fminf(fmaxf(jy, -3.f), 3.f));
    unsigned long long izj = (unsigned long long)lvl100(fminf(fmaxf(jz, -3.f), 3.f));
    float jm = sqrtf((jx * jx + jy * jy) + jz * jz);
    unsigned long long imj = (unsigned long long)lvl100(jm);
    sidx[i] = ix | (iy << 8) | (iz << 16) | (im << 24) |
              (ixj << 32) | (iyj << 40) | (izj << 48) | (imj << 56);
    float ft = (ti / 32768.0f) * 32767.0f;
    int k = (int)rintf(ft);
    tidx[i] = (unsigned int)min(max(k, 0), TSN - 1);
}

// ---------------------------------------------------------------------------
// Main (round-3 known-good body): one wave covers all 2048 dims (32/lane).
// Unconditional coalesced W_t row loads, CSA popcount of sign words,
// LDS block reduce -> one block row, atomicAdd'ed into partial2[blk & 31].
// Exact integer sums -> order-independent, bit-deterministic.
// Chain depth per address = NBLK/NSPLIT = 32 (depth 1024 cost ~205us in R5;
// depth 32 ~6us worst-case, hidden by staggered block completion).
// ---------------------------------------------------------------------------
__global__ __launch_bounds__(256) void main_k(
    const float* __restrict__ Wt,
    const unsigned int* __restrict__ packed2,
    const unsigned long long* __restrict__ sidx,
    const unsigned int* __restrict__ tidx,
    float* __restrict__ partial2, int spw, int n)
{
    __shared__ float red[4][DIM];
    const int tid = threadIdx.x;
    const int l   = tid & 63;
    const int wv  = tid >> 6;
    int gw = blockIdx.x * 4 + wv;
    int s0 = gw * spw;
    int s1 = min(s0 + spw, n);

    float4 acc[8];
    #pragma unroll
    for (int k = 0; k < 8; ++k) acc[k] = make_float4(0.f, 0.f, 0.f, 0.f);

    #pragma unroll 2
    for (int s = s0; s < s1; ++s) {
        int su = __builtin_amdgcn_readfirstlane(s);
        unsigned long long sp = sidx[su];
        unsigned int ti = tidx[su];
        const float4* rowp = (const float4*)(Wt + (size_t)ti * DIM);

        unsigned int i_x  = (unsigned int)(sp)       & 0xffu;
        unsigned int i_y  = (unsigned int)(sp >> 8)  & 0xffu;
        unsigned int i_z  = (unsigned int)(sp >> 16) & 0xffu;
        unsigned int i_m  = (unsigned int)(sp >> 24) & 0xffu;
        unsigned int i_xj = (unsigned int)(sp >> 32) & 0xffu;
        unsigned int i_yj = (unsigned int)(sp >> 40) & 0xffu;
        unsigned int i_zj = (unsigned int)(sp >> 48) & 0xffu;
        unsigned int i_mj = (unsigned int)(sp >> 56) & 0xffu;

        unsigned int Bx  = packed2[(0 * LEVELS + i_x ) * 64 + l];
        unsigned int By  = packed2[(1 * LEVELS + i_y ) * 64 + l];
        unsigned int Bz  = packed2[(2 * LEVELS + i_z ) * 64 + l];
        unsigned int Bm  = packed2[(3 * LEVELS + i_m ) * 64 + l];
        unsigned int Bxj = packed2[(4 * LEVELS + i_xj) * 64 + l];
        unsigned int Byj = packed2[(5 * LEVELS + i_yj) * 64 + l];
        unsigned int Bzj = packed2[(6 * LEVELS + i_zj) * 64 + l];
        unsigned int Bmj = packed2[(7 * LEVELS + i_mj) * 64 + l];

        unsigned int e1 = Bx ^ Bm,  e2 = By ^ Bm,  e3 = Bz ^ Bm;
        unsigned int e4 = Bxj ^ Bmj, e5 = Byj ^ Bmj, e6 = Bzj ^ Bmj;
        unsigned int ta  = e1 ^ e2;
        unsigned int sA  = ta ^ e3;
        unsigned int cA  = (e1 & e2) | (e3 & ta);
        unsigned int tb2 = e4 ^ e5;
        unsigned int sB  = tb2 ^ e6;
        unsigned int cB  = (e4 & e5) | (e6 & tb2);
        unsigned int ones  = sA ^ sB;
        unsigned int cc    = sA & sB;
        unsigned int tc    = cA ^ cB;
        unsigned int twos  = tc ^ cc;
        unsigned int fours = (cA & cB) | (cc & tc);

        #pragma unroll
        for (int k = 0; k < 8; ++k) {
            float4 wt4 = rowp[64 * k + l];
            #pragma unroll
            for (int j = 0; j < 4; ++j) {
                int p = 4 * k + j;
                int v = ((ones >> p) & 1) + 2 * ((twos >> p) & 1)
                      + 4 * ((fours >> p) & 1);
                float sgn = (float)(6 - 2 * v);
                float* a = (float*)&acc[k];
                float* wf = (float*)&wt4;
                a[j] = fmaf(sgn, wf[j], a[j]);
            }
        }
    }

    float4* redw = (float4*)red[wv];
    #pragma unroll
    for (int k = 0; k < 8; ++k) redw[64 * k + l] = acc[k];
    __syncthreads();

    float4 o0 = make_float4(0.f, 0.f, 0.f, 0.f);
    float4 o1 = make_float4(0.f, 0.f, 0.f, 0.f);
    #pragma unroll
    for (int r = 0; r < 4; ++r) {
        float4 a = ((float4*)red[r])[2 * tid];
        float4 b = ((float4*)red[r])[2 * tid + 1];
        o0.x += a.x; o0.y += a.y; o0.z += a.z; o0.w += a.w;
        o1.x += b.x; o1.y += b.y; o1.z += b.z; o1.w += b.w;
    }
    float* prow = partial2 + (size_t)(blockIdx.x & (NSPLIT - 1)) * DIM + tid * 8;
    atomicAdd(prow + 0, o0.x); atomicAdd(prow + 1, o0.y);
    atomicAdd(prow + 2, o0.z); atomicAdd(prow + 3, o0.w);
    atomicAdd(prow + 4, o1.x); atomicAdd(prow + 5, o1.y);
    atomicAdd(prow + 6, o1.z); atomicAdd(prow + 7, o1.w);
}

// ---------------------------------------------------------------------------
// Final reduce + tanh: sum the 32 partial rows per dim.
// ---------------------------------------------------------------------------
__global__ __launch_bounds__(256) void reduce2_k(
    const float* __restrict__ partial2, float* __restrict__ out)
{
    int d = blockIdx.x * 256 + threadIdx.x;
    float s = 0.f;
    #pragma unroll
    for (int b = 0; b < NSPLIT; ++b) s += partial2[(size_t)b * DIM + d];
    out[d] = tanhf(s);
}

// ---------------------------------------------------------------------------
extern "C" void kernel_launch(void* const* d_in, const int* in_sizes, int n_in,
                              void* d_out, int out_size, void* d_ws, size_t ws_size,
                              hipStream_t stream)
{
    const float* inp = (const float*)d_in[0];
    const float* wx  = (const float*)d_in[1];
    const float* wy  = (const float*)d_in[2];
    const float* wz  = (const float*)d_in[3];
    const float* wm  = (const float*)d_in[4];
    const float* wxj = (const float*)d_in[5];
    const float* wyj = (const float*)d_in[6];
    const float* wzj = (const float*)d_in[7];
    const float* wmj = (const float*)d_in[8];
    const float* wt  = (const float*)d_in[9];
    int n = in_sizes[0] / 4;

    char* ws = (char*)d_ws;
    unsigned int* packed2 = (unsigned int*)ws;        // 204800 B used
    size_t off = 256 * 1024;
    unsigned long long* sidx = (unsigned long long*)(ws + off);
    off += (size_t)n * 8;
    unsigned int* tidx = (unsigned int*)(ws + off);
    off += (size_t)n * 4;
    off = (off + 255) & ~(size_t)255;
    float* partial2 = (float*)(ws + off);             // NSPLIT x DIM
    off += (size_t)NSPLIT * DIM * 4;

    int idx_blocks = (n + 255) / 256;
    hipLaunchKernelGGL(prep_k,
                       dim3(PACK_BLOCKS + ZERO_BLOCKS + idx_blocks), dim3(256), 0, stream,
                       wx, wy, wz, wm, wxj, wyj, wzj, wmj,
                       inp, packed2, sidx, tidx, partial2, n);
    int spw = (n + NBLK * 4 - 1) / (NBLK * 4);
    hipLaunchKernelGGL(main_k, dim3(NBLK), dim3(256), 0, stream,
                       wt, packed2, sidx, tidx, partial2, spw, n);
    hipLaunchKernelGGL(reduce2_k, dim3(DIM / 256), dim3(256), 0, stream,
                       partial2, (float*)d_out);
}

// Round 10
// 51.990 us; speedup vs baseline: 1.6777x; 1.6777x over previous
//
#include <hip/hip_runtime.h>
#include <hip/hip_bf16.h>
#include <math.h>

#define DIM     2048
#define LEVELS  100
#define TSN     32768
#define NBLK    1024
#define NSPLIT  32
#define SPW     8         // samples per wave: n=32768 / (1024 blk * 4 waves)
#define PACK_BLOCKS 200   // 8 tables x 25 level-groups (4 levels/block)

// map value in [-3,3] to level index 0..99 (round-half-even like jnp.round)
__device__ __forceinline__ int lvl100(float v) {
    float f = ((v + 3.0f) / 6.0f) * 99.0f;
    int k = (int)rintf(f);
    return min(max(k, 0), LEVELS - 1);
}

// ---------------------------------------------------------------------------
// Fused prep: blocks [0,200) pack the 8 bipolar tables into permuted sign
// words; remaining blocks compute per-sample indices.
// packed2[tab][level][l] (uint32): bit (4k+j) = sign(W[tab][level][256k+4l+j])
// so lane l of a wave owns dims {256k+4l+j}.
// ---------------------------------------------------------------------------
__global__ __launch_bounds__(256) void prep_k(
    const float* __restrict__ w0, const float* __restrict__ w1,
    const float* __restrict__ w2, const float* __restrict__ w3,
    const float* __restrict__ w4, const float* __restrict__ w5,
    const float* __restrict__ w6, const float* __restrict__ w7,
    const float* __restrict__ inp,
    unsigned int* __restrict__ packed2,
    unsigned long long* __restrict__ sidx,
    unsigned int* __restrict__ tidx, int n)
{
    if (blockIdx.x < PACK_BLOCKS) {
        int tab = blockIdx.x / 25;
        int lg  = blockIdx.x - tab * 25;
        int l   = threadIdx.x & 63;
        int level = lg * 4 + (threadIdx.x >> 6);
        const float* w;
        switch (tab) {
            case 0: w = w0; break; case 1: w = w1; break;
            case 2: w = w2; break; case 3: w = w3; break;
            case 4: w = w4; break; case 5: w = w5; break;
            case 6: w = w6; break; default: w = w7; break;
        }
        const float* base = w + (size_t)level * DIM + 4 * l;
        unsigned int word = 0;
        #pragma unroll
        for (int k = 0; k < 8; ++k) {
            float4 a = *(const float4*)(base + 256 * k);
            word |= (a.x < 0.f ? 1u : 0u) << (4 * k);
            word |= (a.y < 0.f ? 1u : 0u) << (4 * k + 1);
            word |= (a.z < 0.f ? 1u : 0u) << (4 * k + 2);
            word |= (a.w < 0.f ? 1u : 0u) << (4 * k + 3);
        }
        packed2[(tab * LEVELS + level) * 64 + l] = word;
        return;
    }
    int i = (blockIdx.x - PACK_BLOCKS) * 256 + threadIdx.x;
    if (i >= n) return;
    float t0 = inp[0];
    float ti = inp[i * 4] - t0;
    float x = inp[i * 4 + 1], y = inp[i * 4 + 2], z = inp[i * 4 + 3];
    float xc = fminf(fmaxf(x, -3.f), 3.f);
    float yc = fminf(fmaxf(y, -3.f), 3.f);
    float zc = fminf(fmaxf(z, -3.f), 3.f);
    unsigned long long ix = (unsigned long long)lvl100(xc);
    unsigned long long iy = (unsigned long long)lvl100(yc);
    unsigned long long iz = (unsigned long long)lvl100(zc);
    float mag = sqrtf((x * x + y * y) + z * z);   // unclipped, ref assoc order
    unsigned long long im = (unsigned long long)lvl100(mag);
    float jx = 0.f, jy = 0.f, jz = 0.f;
    if (i > 0) {
        float tp = inp[(i - 1) * 4] - t0;
        float dt = ti - tp;                        // dt from offset times, as ref
        jx = (x - inp[(i - 1) * 4 + 1]) / dt;
        jy = (y - inp[(i - 1) * 4 + 2]) / dt;
        jz = (z - inp[(i - 1) * 4 + 3]) / dt;
    }
    unsigned long long ixj = (unsigned long long)lvl100(fminf(fmaxf(jx, -3.f), 3.f));
    unsigned long long iyj = (unsigned long long)lvl100(fminf(fmaxf(jy, -3.f), 3.f));
    unsigned long long izj = (unsigned long long)lvl100(fminf(fmaxf(jz, -3.f), 3.f));
    float jm = sqrtf((jx * jx + jy * jy) + jz * jz);
    unsigned long long imj = (unsigned long long)lvl100(jm);
    sidx[i] = ix | (iy << 8) | (iz << 16) | (im << 24) |
              (ixj << 32) | (iyj << 40) | (izj << 48) | (imj << 56);
    float ft = (ti / 32768.0f) * 32767.0f;
    int k = (int)rintf(ft);
    tidx[i] = (unsigned int)min(max(k, 0), TSN - 1);
}

// ---------------------------------------------------------------------------
// Main (R3 structure + early-resolved dedup): one wave covers all 2048 dims
// (32/lane). All 8 sample indices preloaded at chunk top -> "new row" flags
// known early; body fully unrolled; row loads guarded by wave-uniform scalar
// branches (skip ~35% duplicate 8KB row reloads without the R4 serialization,
// whose condition depended on a load inside the loop). LDS block reduce ->
// one partial row per block. Exact integer sums.
// ---------------------------------------------------------------------------
__global__ __launch_bounds__(256) void main_k(
    const float* __restrict__ Wt,
    const unsigned int* __restrict__ packed2,
    const unsigned long long* __restrict__ sidx,
    const unsigned int* __restrict__ tidx,
    float* __restrict__ partials, int spw, int n)
{
    __shared__ float red[4][DIM];
    const int tid = threadIdx.x;
    const int l   = tid & 63;
    const int wv  = tid >> 6;
    int gw = blockIdx.x * 4 + wv;
    int s0 = gw * spw;
    int cnt = min(spw, n - s0);            // samples this wave (<= SPW)

    float4 acc[8];
    #pragma unroll
    for (int k = 0; k < 8; ++k) acc[k] = make_float4(0.f, 0.f, 0.f, 0.f);
    float4 row[8];

    if (cnt > 0) {
        int su0 = __builtin_amdgcn_readfirstlane(s0);
        // preload all indices for the chunk (uniform -> scalar loads, one wait)
        unsigned int       tloc[SPW];
        unsigned long long sloc[SPW];
        #pragma unroll
        for (int k = 0; k < SPW; ++k) {
            int sk = su0 + (k < cnt ? k : cnt - 1);  // clamp, uniform
            tloc[k] = tidx[sk];
            sloc[k] = sidx[sk];
        }

        unsigned int tprev = 0xffffffffu;
        #pragma unroll
        for (int k = 0; k < SPW; ++k) {
            if (k < cnt) {
                if (tloc[k] != tprev) {              // uniform, known early
                    const float4* rowp =
                        (const float4*)(Wt + (size_t)tloc[k] * DIM);
                    #pragma unroll
                    for (int q = 0; q < 8; ++q) row[q] = rowp[64 * q + l];
                }
                tprev = tloc[k];

                unsigned long long sp = sloc[k];
                unsigned int i_x  = (unsigned int)(sp)       & 0xffu;
                unsigned int i_y  = (unsigned int)(sp >> 8)  & 0xffu;
                unsigned int i_z  = (unsigned int)(sp >> 16) & 0xffu;
                unsigned int i_m  = (unsigned int)(sp >> 24) & 0xffu;
                unsigned int i_xj = (unsigned int)(sp >> 32) & 0xffu;
                unsigned int i_yj = (unsigned int)(sp >> 40) & 0xffu;
                unsigned int i_zj = (unsigned int)(sp >> 48) & 0xffu;
                unsigned int i_mj = (unsigned int)(sp >> 56) & 0xffu;

                unsigned int Bx  = packed2[(0 * LEVELS + i_x ) * 64 + l];
                unsigned int By  = packed2[(1 * LEVELS + i_y ) * 64 + l];
                unsigned int Bz  = packed2[(2 * LEVELS + i_z ) * 64 + l];
                unsigned int Bm  = packed2[(3 * LEVELS + i_m ) * 64 + l];
                unsigned int Bxj = packed2[(4 * LEVELS + i_xj) * 64 + l];
                unsigned int Byj = packed2[(5 * LEVELS + i_yj) * 64 + l];
                unsigned int Bzj = packed2[(6 * LEVELS + i_zj) * 64 + l];
                unsigned int Bmj = packed2[(7 * LEVELS + i_mj) * 64 + l];

                unsigned int e1 = Bx ^ Bm,  e2 = By ^ Bm,  e3 = Bz ^ Bm;
                unsigned int e4 = Bxj ^ Bmj, e5 = Byj ^ Bmj, e6 = Bzj ^ Bmj;
                unsigned int ta  = e1 ^ e2;
                unsigned int sA  = ta ^ e3;
                unsigned int cA  = (e1 & e2) | (e3 & ta);
                unsigned int tb2 = e4 ^ e5;
                unsigned int sB  = tb2 ^ e6;
                unsigned int cB  = (e4 & e5) | (e6 & tb2);
                unsigned int ones  = sA ^ sB;
                unsigned int cc    = sA & sB;
                unsigned int tc    = cA ^ cB;
                unsigned int twos  = tc ^ cc;
                unsigned int fours = (cA & cB) | (cc & tc);

                #pragma unroll
                for (int q = 0; q < 8; ++q) {
                    #pragma unroll
                    for (int j = 0; j < 4; ++j) {
                        int p = 4 * q + j;
                        int v = ((ones >> p) & 1) + 2 * ((twos >> p) & 1)
                              + 4 * ((fours >> p) & 1);
                        float sgn = (float)(6 - 2 * v);
                        float* a = (float*)&acc[q];
                        float* wf = (float*)&row[q];
                        a[j] = fmaf(sgn, wf[j], a[j]);
                    }
                }
            }
        }
    }

    float4* redw = (float4*)red[wv];
    #pragma unroll
    for (int k = 0; k < 8; ++k) redw[64 * k + l] = acc[k];
    __syncthreads();

    float4 o0 = make_float4(0.f, 0.f, 0.f, 0.f);
    float4 o1 = make_float4(0.f, 0.f, 0.f, 0.f);
    #pragma unroll
    for (int r = 0; r < 4; ++r) {
        float4 a = ((float4*)red[r])[2 * tid];
        float4 b = ((float4*)red[r])[2 * tid + 1];
        o0.x += a.x; o0.y += a.y; o0.z += a.z; o0.w += a.w;
        o1.x += b.x; o1.y += b.y; o1.z += b.z; o1.w += b.w;
    }
    float4* pout = (float4*)(partials + (size_t)blockIdx.x * DIM + tid * 8);
    pout[0] = o0;
    pout[1] = o1;
}

// ---------------------------------------------------------------------------
// Stage-1 reduce: grid (DIM/256, NSPLIT), coalesced row sums.
// ---------------------------------------------------------------------------
__global__ __launch_bounds__(256) void reduce1_k(
    const float* __restrict__ partials, float* __restrict__ partial2,
    int rows_per, int nblk)
{
    int d = blockIdx.x * 256 + threadIdx.x;
    int r0 = blockIdx.y * rows_per;
    int r1 = min(r0 + rows_per, nblk);
    float s = 0.f;
    for (int b = r0; b < r1; ++b) s += partials[(size_t)b * DIM + d];
    partial2[(size_t)blockIdx.y * DIM + d] = s;
}

// ---------------------------------------------------------------------------
// Stage-2 reduce + tanh.
// ---------------------------------------------------------------------------
__global__ __launch_bounds__(256) void reduce2_k(
    const float* __restrict__ partial2, float* __restrict__ out)
{
    int d = blockIdx.x * 256 + threadIdx.x;
    float s = 0.f;
    #pragma unroll
    for (int b = 0; b < NSPLIT; ++b) s += partial2[(size_t)b * DIM + d];
    out[d] = tanhf(s);
}

// ---------------------------------------------------------------------------
extern "C" void kernel_launch(void* const* d_in, const int* in_sizes, int n_in,
                              void* d_out, int out_size, void* d_ws, size_t ws_size,
                              hipStream_t stream)
{
    const float* inp = (const float*)d_in[0];
    const float* wx  = (const float*)d_in[1];
    const float* wy  = (const float*)d_in[2];
    const float* wz  = (const float*)d_in[3];
    const float* wm  = (const float*)d_in[4];
    const float* wxj = (const float*)d_in[5];
    const float* wyj = (const float*)d_in[6];
    const float* wzj = (const float*)d_in[7];
    const float* wmj = (const float*)d_in[8];
    const float* wt  = (const float*)d_in[9];
    int n = in_sizes[0] / 4;

    char* ws = (char*)d_ws;
    unsigned int* packed2 = (unsigned int*)ws;        // 204800 B used
    size_t off = 256 * 1024;
    unsigned long long* sidx = (unsigned long long*)(ws + off);
    off += (size_t)n * 8;
    unsigned int* tidx = (unsigned int*)(ws + off);
    off += (size_t)n * 4;
    off = (off + 255) & ~(size_t)255;

    float* partial2 = (float*)(ws + off);             // NSPLIT x DIM
    off += (size_t)NSPLIT * DIM * 4;

    int nblk = NBLK;
    while (nblk > 32 && off + (size_t)nblk * DIM * 4 > ws_size) nblk >>= 1;
    float* partials = (float*)(ws + off);

    int idx_blocks = (n + 255) / 256;
    hipLaunchKernelGGL(prep_k, dim3(PACK_BLOCKS + idx_blocks), dim3(256), 0, stream,
                       wx, wy, wz, wm, wxj, wyj, wzj, wmj,
                       inp, packed2, sidx, tidx, n);
    int spw = (n + nblk * 4 - 1) / (nblk * 4);
    hipLaunchKernelGGL(main_k, dim3(nblk), dim3(256), 0, stream,
                       wt, packed2, sidx, tidx, partials, spw, n);
    int rows_per = (nblk + NSPLIT - 1) / NSPLIT;
    hipLaunchKernelGGL(reduce1_k, dim3(DIM / 256, NSPLIT), dim3(256), 0, stream,
                       partials, partial2, rows_per, nblk);
    hipLaunchKernelGGL(reduce2_k, dim3(DIM / 256), dim3(256), 0, stream,
                       partial2, (float*)d_out);
}